// Round 1
// baseline (1142.696 us; speedup 1.0000x reference)
//
#include <hip/hip_runtime.h>

typedef unsigned short u16;
typedef unsigned int   u32;

using short8  = __attribute__((ext_vector_type(8))) short;
using floatx4 = __attribute__((ext_vector_type(4))) float;

// ---------- constants ----------
#define Bb   16
#define Hh   56
#define Ww   56
#define Cc   512
#define NHh  16
#define HDd  32
#define HIDh 2048
#define Ll   (Hh*Ww)          // 3136
#define Mm   (Bb*Ll)          // 50176
#define SCALE 0.17677669529663687f

// ---------- helpers ----------
__device__ __forceinline__ u16 f2bf(float f) {
  union { float f; u32 u; } v; v.f = f;
  u32 r = (v.u + 0x7fffu + ((v.u >> 16) & 1u)) >> 16;
  return (u16)r;
}
__device__ __forceinline__ float bf2f_lo(u32 u) {
  union { u32 u; float f; } v; v.u = u << 16; return v.f;
}
__device__ __forceinline__ float bf2f_hi(u32 u) {
  union { u32 u; float f; } v; v.u = u & 0xffff0000u; return v.f;
}
__device__ __forceinline__ float gelu_f(float x) {
  return 0.5f * x * (1.f + erff(x * 0.70710678118654752f));
}
__device__ __forceinline__ void gld_lds16(const u16* g, u16* l) {
  __builtin_amdgcn_global_load_lds(
      (__attribute__((address_space(1))) void*)(void*)g,
      (__attribute__((address_space(3))) void*)(void*)l,
      16, 0, 0);
}

// ---------- weight convert+transpose: Wt[n][k] = bf16(W[k][n]) ----------
__global__ void wcvt_k(const float* __restrict__ W, u16* __restrict__ Wt,
                       int K, int N) {
  int idx = blockIdx.x * 256 + threadIdx.x;     // over N*K
  int n = idx / K;
  int k = idx - n * K;
  Wt[idx] = f2bf(W[(size_t)k * N + n]);
}

// ---------- layernorm (fp32 in -> bf16 out), one wave per row ----------
__global__ __launch_bounds__(256)
void ln_k(const float* __restrict__ x, const float* __restrict__ g,
          const float* __restrict__ b, u16* __restrict__ out) {
  const int row  = blockIdx.x * 4 + (threadIdx.x >> 6);
  const int lane = threadIdx.x & 63;
  const float* xr = x + (size_t)row * Cc + lane * 8;
  float4 v0 = *(const float4*)xr;
  float4 v1 = *(const float4*)(xr + 4);
  float s  = v0.x+v0.y+v0.z+v0.w + v1.x+v1.y+v1.z+v1.w;
  float s2 = v0.x*v0.x+v0.y*v0.y+v0.z*v0.z+v0.w*v0.w
           + v1.x*v1.x+v1.y*v1.y+v1.z*v1.z+v1.w*v1.w;
  #pragma unroll
  for (int off = 32; off >= 1; off >>= 1) {
    s  += __shfl_xor(s,  off);
    s2 += __shfl_xor(s2, off);
  }
  float mu  = s  * (1.f/512.f);
  float var = s2 * (1.f/512.f) - mu*mu;
  float rs  = rsqrtf(var + 1e-5f);
  float4 ga = *(const float4*)(g + lane*8);
  float4 gb = *(const float4*)(g + lane*8 + 4);
  float4 ba = *(const float4*)(b + lane*8);
  float4 bb = *(const float4*)(b + lane*8 + 4);
  float o0 = (v0.x-mu)*rs*ga.x + ba.x;
  float o1 = (v0.y-mu)*rs*ga.y + ba.y;
  float o2 = (v0.z-mu)*rs*ga.z + ba.z;
  float o3 = (v0.w-mu)*rs*ga.w + ba.w;
  float o4 = (v1.x-mu)*rs*gb.x + bb.x;
  float o5 = (v1.y-mu)*rs*gb.y + bb.y;
  float o6 = (v1.z-mu)*rs*gb.z + bb.z;
  float o7 = (v1.w-mu)*rs*gb.w + bb.w;
  u32 w0 = (u32)f2bf(o0) | ((u32)f2bf(o1) << 16);
  u32 w1 = (u32)f2bf(o2) | ((u32)f2bf(o3) << 16);
  u32 w2 = (u32)f2bf(o4) | ((u32)f2bf(o5) << 16);
  u32 w3 = (u32)f2bf(o6) | ((u32)f2bf(o7) << 16);
  *(uint4*)(out + (size_t)row * Cc + lane * 8) = make_uint4(w0, w1, w2, w3);
}

// ---------- GEMM: out[M,N] = A[M,K](bf16) @ Bt[N,K](bf16)^T + bias ----------
// MODE 0: store bf16           MODE 1: gelu -> bf16
// MODE 2: + res(fp32) -> fp32
template<int MODE>
__global__ __launch_bounds__(256, 2)
void gemm_bt(const u16* __restrict__ A, const u16* __restrict__ Bt,
             const float* __restrict__ bias, const float* __restrict__ res,
             void* __restrict__ outp, int M, int N, int K) {
  __shared__ u16 As[128 * 32];
  __shared__ u16 Bs[128 * 32];
  const int tid  = threadIdx.x;
  const int lane = tid & 63;
  const int wave = tid >> 6;
  const int wm = (wave >> 1) * 64;
  const int wn = (wave & 1) * 64;
  const int m0 = blockIdx.x * 128;
  const int n0 = blockIdx.y * 128;
  const int quad = lane >> 4;
  const int l16  = lane & 15;

  floatx4 acc[4][4];
  #pragma unroll
  for (int i = 0; i < 4; i++)
    #pragma unroll
    for (int j = 0; j < 4; j++) acc[i][j] = (floatx4)0.f;

  // staging: 512 x 16B chunks per tile; chunk c -> row c>>2, col (c&3)*8
  const int r0  = tid >> 2;
  const int cc0 = (tid & 3) * 8;
  const u16* Ag = A  + (size_t)m0 * K;
  const u16* Bg = Bt + (size_t)n0 * K;

  for (int k0 = 0; k0 < K; k0 += 32) {
    gld_lds16(Ag + (size_t)r0        * K + k0 + cc0, &As[wave * 512]);
    gld_lds16(Ag + (size_t)(r0 + 64) * K + k0 + cc0, &As[2048 + wave * 512]);
    gld_lds16(Bg + (size_t)r0        * K + k0 + cc0, &Bs[wave * 512]);
    gld_lds16(Bg + (size_t)(r0 + 64) * K + k0 + cc0, &Bs[2048 + wave * 512]);
    __syncthreads();
    short8 af[4], bf[4];
    #pragma unroll
    for (int mi = 0; mi < 4; mi++)
      af[mi] = *(const short8*)&As[(wm + mi*16 + l16) * 32 + quad * 8];
    #pragma unroll
    for (int ni = 0; ni < 4; ni++)
      bf[ni] = *(const short8*)&Bs[(wn + ni*16 + l16) * 32 + quad * 8];
    #pragma unroll
    for (int mi = 0; mi < 4; mi++)
      #pragma unroll
      for (int ni = 0; ni < 4; ni++)
        acc[mi][ni] = __builtin_amdgcn_mfma_f32_16x16x32_bf16(
            af[mi], bf[ni], acc[mi][ni], 0, 0, 0);
    __syncthreads();
  }

  const int mrow = m0 + wm + quad * 4;
  const int ncol = n0 + wn + l16;
  #pragma unroll
  for (int ni = 0; ni < 4; ni++) {
    const int n = ncol + ni * 16;
    const float bv = bias[n];
    #pragma unroll
    for (int mi = 0; mi < 4; mi++) {
      #pragma unroll
      for (int r = 0; r < 4; r++) {
        const int m = mrow + mi * 16 + r;
        const size_t idx = (size_t)m * N + n;
        float v = acc[mi][ni][r] + bv;
        if (MODE == 0)      ((u16*)outp)[idx] = f2bf(v);
        else if (MODE == 1) ((u16*)outp)[idx] = f2bf(gelu_f(v));
        else                ((float*)outp)[idx] = v + res[idx];
      }
    }
  }
}

// ---------- windowed attention, one wave per (window, head) ----------
// Q/K/V are bf16 (B,L,C); output written window-reversed to (B,L,C) bf16.
__global__ __launch_bounds__(64)
void attn_k(const u16* __restrict__ Q, const u16* __restrict__ Kb,
            const u16* __restrict__ Vb, const float* __restrict__ rel,
            u16* __restrict__ O) {
  const int win  = blockIdx.x;          // 0..1023
  const int head = blockIdx.y;          // 0..15
  const int b    = win >> 6;
  const int wh   = (win >> 3) & 7;
  const int ww   = win & 7;
  const int lane = threadIdx.x;

  __shared__ float Ks[49][36];
  __shared__ float Vs[49][36];

  const bool active = lane < 49;
  size_t rowbase = 0;
  float q[32];
  if (active) {
    const int i = lane / 7, j = lane - 7 * (lane / 7);
    const int l = (wh * 7 + i) * Ww + ww * 7 + j;
    rowbase = ((size_t)(b * Ll + l)) * Cc + head * HDd;
    const uint4* qp = (const uint4*)(Q  + rowbase);
    const uint4* kp = (const uint4*)(Kb + rowbase);
    const uint4* vp = (const uint4*)(Vb + rowbase);
    #pragma unroll
    for (int c = 0; c < 4; c++) {
      uint4 qv = qp[c], kv = kp[c], vv = vp[c];
      q[c*8+0] = bf2f_lo(qv.x) * SCALE; q[c*8+1] = bf2f_hi(qv.x) * SCALE;
      q[c*8+2] = bf2f_lo(qv.y) * SCALE; q[c*8+3] = bf2f_hi(qv.y) * SCALE;
      q[c*8+4] = bf2f_lo(qv.z) * SCALE; q[c*8+5] = bf2f_hi(qv.z) * SCALE;
      q[c*8+6] = bf2f_lo(qv.w) * SCALE; q[c*8+7] = bf2f_hi(qv.w) * SCALE;
      *(float4*)&Ks[lane][c*8]   = make_float4(bf2f_lo(kv.x), bf2f_hi(kv.x),
                                               bf2f_lo(kv.y), bf2f_hi(kv.y));
      *(float4*)&Ks[lane][c*8+4] = make_float4(bf2f_lo(kv.z), bf2f_hi(kv.z),
                                               bf2f_lo(kv.w), bf2f_hi(kv.w));
      *(float4*)&Vs[lane][c*8]   = make_float4(bf2f_lo(vv.x), bf2f_hi(vv.x),
                                               bf2f_lo(vv.y), bf2f_hi(vv.y));
      *(float4*)&Vs[lane][c*8+4] = make_float4(bf2f_lo(vv.z), bf2f_hi(vv.z),
                                               bf2f_lo(vv.w), bf2f_hi(vv.w));
    }
  }
  __syncthreads();
  if (!active) return;

  const float* rb = rel + ((size_t)head * 49 + lane) * 49;
  float s[49];
  float mx = -1e30f;
  #pragma unroll
  for (int m = 0; m < 49; m++) {
    float d = 0.f;
    #pragma unroll
    for (int c = 0; c < 8; c++) {
      float4 kk = *(const float4*)&Ks[m][c*4];
      d += q[c*4+0]*kk.x + q[c*4+1]*kk.y + q[c*4+2]*kk.z + q[c*4+3]*kk.w;
    }
    d += rb[m];
    s[m] = d;
    mx = fmaxf(mx, d);
  }
  float sum = 0.f;
  #pragma unroll
  for (int m = 0; m < 49; m++) { float e = __expf(s[m] - mx); s[m] = e; sum += e; }
  const float inv = 1.f / sum;

  float acc[32];
  #pragma unroll
  for (int d = 0; d < 32; d++) acc[d] = 0.f;
  #pragma unroll
  for (int m = 0; m < 49; m++) {
    const float p = s[m];
    #pragma unroll
    for (int c = 0; c < 8; c++) {
      float4 vv = *(const float4*)&Vs[m][c*4];
      acc[c*4+0] += p*vv.x; acc[c*4+1] += p*vv.y;
      acc[c*4+2] += p*vv.z; acc[c*4+3] += p*vv.w;
    }
  }
  uint4* op = (uint4*)(O + rowbase);
  #pragma unroll
  for (int c = 0; c < 4; c++) {
    u32 w0 = (u32)f2bf(acc[c*8+0]*inv) | ((u32)f2bf(acc[c*8+1]*inv) << 16);
    u32 w1 = (u32)f2bf(acc[c*8+2]*inv) | ((u32)f2bf(acc[c*8+3]*inv) << 16);
    u32 w2 = (u32)f2bf(acc[c*8+4]*inv) | ((u32)f2bf(acc[c*8+5]*inv) << 16);
    u32 w3 = (u32)f2bf(acc[c*8+6]*inv) | ((u32)f2bf(acc[c*8+7]*inv) << 16);
    op[c] = make_uint4(w0, w1, w2, w3);
  }
}

// ---------- launch ----------
extern "C" void kernel_launch(void* const* d_in, const int* in_sizes, int n_in,
                              void* d_out, int out_size, void* d_ws, size_t ws_size,
                              hipStream_t stream) {
  (void)in_sizes; (void)n_in; (void)out_size; (void)ws_size;
  const float* x    = (const float*)d_in[0];
  const float* Wq   = (const float*)d_in[1];
  const float* bq   = (const float*)d_in[2];
  const float* Wk   = (const float*)d_in[3];
  const float* bk   = (const float*)d_in[4];
  const float* Wv   = (const float*)d_in[5];
  const float* bv   = (const float*)d_in[6];
  const float* Wp   = (const float*)d_in[7];
  const float* bp   = (const float*)d_in[8];
  const float* rel  = (const float*)d_in[9];
  const float* g1   = (const float*)d_in[10];
  const float* b1   = (const float*)d_in[11];
  const float* g2   = (const float*)d_in[12];
  const float* b2   = (const float*)d_in[13];
  const float* W1   = (const float*)d_in[14];
  const float* bfc1 = (const float*)d_in[15];
  const float* W2   = (const float*)d_in[16];
  const float* bfc2 = (const float*)d_in[17];
  float* out = (float*)d_out;

  // workspace layout (bytes, all well-aligned)
  u16* wWq  = (u16*)d_ws;                         // 512*512
  u16* wWk  = wWq + 512*512;
  u16* wWv  = wWk + 512*512;
  u16* wWp  = wWv + 512*512;
  u16* wW1  = wWp + 512*512;                      // 2048*512 (N rows, K cols)
  u16* wW2  = wW1 + (size_t)512*2048;             // 512*2048
  u16* hbuf = wW2 + (size_t)512*2048;             // M*512 bf16 (LN1 out, later LN2 out)
  u16* Qb   = hbuf + (size_t)Mm * Cc;             // region reused later by MLP hidden
  u16* Kbf  = Qb   + (size_t)Mm * Cc;
  u16* Vbf  = Kbf  + (size_t)Mm * Cc;
  u16* Obuf = Vbf  + (size_t)Mm * Cc;
  u16* hid  = Qb;                                  // M*2048 bf16, overlays Q/K/V/Obuf
  float* x2 = (float*)(Obuf + (size_t)Mm * Cc);    // M*512 fp32
  u16* h2   = hbuf;

  // weights -> bf16 transposed
  wcvt_k<<<(512*512)/256,  256, 0, stream>>>(Wq, wWq, 512, 512);
  wcvt_k<<<(512*512)/256,  256, 0, stream>>>(Wk, wWk, 512, 512);
  wcvt_k<<<(512*512)/256,  256, 0, stream>>>(Wv, wWv, 512, 512);
  wcvt_k<<<(512*512)/256,  256, 0, stream>>>(Wp, wWp, 512, 512);
  wcvt_k<<<(512*2048)/256, 256, 0, stream>>>(W1, wW1, 512, 2048);
  wcvt_k<<<(512*2048)/256, 256, 0, stream>>>(W2, wW2, 2048, 512);

  // LN1
  ln_k<<<Mm/4, 256, 0, stream>>>(x, g1, b1, hbuf);

  // QKV projections
  dim3 gqkv(Mm/128, 4);
  gemm_bt<0><<<gqkv, 256, 0, stream>>>(hbuf, wWq, bq, nullptr, Qb,  Mm, 512, 512);
  gemm_bt<0><<<gqkv, 256, 0, stream>>>(hbuf, wWk, bk, nullptr, Kbf, Mm, 512, 512);
  gemm_bt<0><<<gqkv, 256, 0, stream>>>(hbuf, wWv, bv, nullptr, Vbf, Mm, 512, 512);

  // attention (window-reversed output)
  attn_k<<<dim3(1024, 16), 64, 0, stream>>>(Qb, Kbf, Vbf, rel, Obuf);

  // proj + residual -> x2 (fp32)
  gemm_bt<2><<<gqkv, 256, 0, stream>>>(Obuf, wWp, bp, x, x2, Mm, 512, 512);

  // LN2
  ln_k<<<Mm/4, 256, 0, stream>>>(x2, g2, b2, h2);

  // MLP
  gemm_bt<1><<<dim3(Mm/128, 16), 256, 0, stream>>>(h2, wW1, bfc1, nullptr, hid, Mm, 2048, 512);
  gemm_bt<2><<<dim3(Mm/128, 4),  256, 0, stream>>>(hid, wW2, bfc2, x2, out,  Mm, 512, 2048);
}

// Round 2
// 1048.108 us; speedup vs baseline: 1.0902x; 1.0902x over previous
//
#include <hip/hip_runtime.h>

typedef unsigned short u16;
typedef unsigned int   u32;

using short8  = __attribute__((ext_vector_type(8))) short;
using floatx4 = __attribute__((ext_vector_type(4))) float;

// ---------- constants ----------
#define Bb   16
#define Hh   56
#define Ww   56
#define Cc   512
#define NHh  16
#define HDd  32
#define HIDh 2048
#define Ll   (Hh*Ww)          // 3136
#define Mm   (Bb*Ll)          // 50176
#define SCALE 0.17677669529663687f

// ---------- helpers ----------
__device__ __forceinline__ u16 f2bf(float f) {
  union { float f; u32 u; } v; v.f = f;
  u32 r = (v.u + 0x7fffu + ((v.u >> 16) & 1u)) >> 16;
  return (u16)r;
}
__device__ __forceinline__ float bf2f(u16 u) {
  union { u32 u; float f; } v; v.u = ((u32)u) << 16; return v.f;
}
__device__ __forceinline__ float bf2f_lo(u32 u) {
  union { u32 u; float f; } v; v.u = u << 16; return v.f;
}
__device__ __forceinline__ float bf2f_hi(u32 u) {
  union { u32 u; float f; } v; v.u = u & 0xffff0000u; return v.f;
}
__device__ __forceinline__ float gelu_f(float x) {
  return 0.5f * x * (1.f + erff(x * 0.70710678118654752f));
}
__device__ __forceinline__ void gld_lds16(const u16* g, u16* l) {
  __builtin_amdgcn_global_load_lds(
      (__attribute__((address_space(1))) void*)(void*)g,
      (__attribute__((address_space(3))) void*)(void*)l,
      16, 0, 0);
}

// ---------- weight convert+transpose: Wt[n][k] = bf16(W[k][n]) ----------
__global__ void wcvt_k(const float* __restrict__ W, u16* __restrict__ Wt,
                       int K, int N) {
  int idx = blockIdx.x * 256 + threadIdx.x;     // over N*K
  int n = idx / K;
  int k = idx - n * K;
  Wt[idx] = f2bf(W[(size_t)k * N + n]);
}

// ---------- concat 3 bias vectors (512 each) ----------
__global__ void bcat_k(const float* __restrict__ a, const float* __restrict__ b,
                       const float* __restrict__ c, float* __restrict__ o) {
  int i = blockIdx.x * 256 + threadIdx.x;   // 0..1535
  float v = (i < 512) ? a[i] : (i < 1024) ? b[i - 512] : c[i - 1024];
  o[i] = v;
}

// ---------- layernorm fp32 in -> bf16 out, one wave per row ----------
__global__ __launch_bounds__(256)
void ln_k(const float* __restrict__ x, const float* __restrict__ g,
          const float* __restrict__ b, u16* __restrict__ out) {
  const int row  = blockIdx.x * 4 + (threadIdx.x >> 6);
  const int lane = threadIdx.x & 63;
  const float* xr = x + (size_t)row * Cc + lane * 8;
  float4 v0 = *(const float4*)xr;
  float4 v1 = *(const float4*)(xr + 4);
  float s  = v0.x+v0.y+v0.z+v0.w + v1.x+v1.y+v1.z+v1.w;
  float s2 = v0.x*v0.x+v0.y*v0.y+v0.z*v0.z+v0.w*v0.w
           + v1.x*v1.x+v1.y*v1.y+v1.z*v1.z+v1.w*v1.w;
  #pragma unroll
  for (int off = 32; off >= 1; off >>= 1) {
    s  += __shfl_xor(s,  off);
    s2 += __shfl_xor(s2, off);
  }
  float mu  = s  * (1.f/512.f);
  float var = s2 * (1.f/512.f) - mu*mu;
  float rs  = rsqrtf(var + 1e-5f);
  float4 ga = *(const float4*)(g + lane*8);
  float4 gb = *(const float4*)(g + lane*8 + 4);
  float4 ba = *(const float4*)(b + lane*8);
  float4 bb = *(const float4*)(b + lane*8 + 4);
  float o0 = (v0.x-mu)*rs*ga.x + ba.x;
  float o1 = (v0.y-mu)*rs*ga.y + ba.y;
  float o2 = (v0.z-mu)*rs*ga.z + ba.z;
  float o3 = (v0.w-mu)*rs*ga.w + ba.w;
  float o4 = (v1.x-mu)*rs*gb.x + bb.x;
  float o5 = (v1.y-mu)*rs*gb.y + bb.y;
  float o6 = (v1.z-mu)*rs*gb.z + bb.z;
  float o7 = (v1.w-mu)*rs*gb.w + bb.w;
  u32 w0 = (u32)f2bf(o0) | ((u32)f2bf(o1) << 16);
  u32 w1 = (u32)f2bf(o2) | ((u32)f2bf(o3) << 16);
  u32 w2 = (u32)f2bf(o4) | ((u32)f2bf(o5) << 16);
  u32 w3 = (u32)f2bf(o6) | ((u32)f2bf(o7) << 16);
  *(uint4*)(out + (size_t)row * Cc + lane * 8) = make_uint4(w0, w1, w2, w3);
}

// ---------- layernorm bf16 in -> bf16 out ----------
__global__ __launch_bounds__(256)
void ln_bf_k(const u16* __restrict__ x, const float* __restrict__ g,
             const float* __restrict__ b, u16* __restrict__ out) {
  const int row  = blockIdx.x * 4 + (threadIdx.x >> 6);
  const int lane = threadIdx.x & 63;
  uint4 xv = *(const uint4*)(x + (size_t)row * Cc + lane * 8);
  float v[8];
  v[0]=bf2f_lo(xv.x); v[1]=bf2f_hi(xv.x); v[2]=bf2f_lo(xv.y); v[3]=bf2f_hi(xv.y);
  v[4]=bf2f_lo(xv.z); v[5]=bf2f_hi(xv.z); v[6]=bf2f_lo(xv.w); v[7]=bf2f_hi(xv.w);
  float s = 0.f, s2 = 0.f;
  #pragma unroll
  for (int i = 0; i < 8; i++) { s += v[i]; s2 += v[i]*v[i]; }
  #pragma unroll
  for (int off = 32; off >= 1; off >>= 1) {
    s  += __shfl_xor(s,  off);
    s2 += __shfl_xor(s2, off);
  }
  float mu  = s  * (1.f/512.f);
  float var = s2 * (1.f/512.f) - mu*mu;
  float rs  = rsqrtf(var + 1e-5f);
  float4 ga = *(const float4*)(g + lane*8);
  float4 gb = *(const float4*)(g + lane*8 + 4);
  float4 ba = *(const float4*)(b + lane*8);
  float4 bb = *(const float4*)(b + lane*8 + 4);
  float o[8];
  o[0]=(v[0]-mu)*rs*ga.x+ba.x; o[1]=(v[1]-mu)*rs*ga.y+ba.y;
  o[2]=(v[2]-mu)*rs*ga.z+ba.z; o[3]=(v[3]-mu)*rs*ga.w+ba.w;
  o[4]=(v[4]-mu)*rs*gb.x+bb.x; o[5]=(v[5]-mu)*rs*gb.y+bb.y;
  o[6]=(v[6]-mu)*rs*gb.z+bb.z; o[7]=(v[7]-mu)*rs*gb.w+bb.w;
  u32 w0 = (u32)f2bf(o[0]) | ((u32)f2bf(o[1]) << 16);
  u32 w1 = (u32)f2bf(o[2]) | ((u32)f2bf(o[3]) << 16);
  u32 w2 = (u32)f2bf(o[4]) | ((u32)f2bf(o[5]) << 16);
  u32 w3 = (u32)f2bf(o[6]) | ((u32)f2bf(o[7]) << 16);
  *(uint4*)(out + (size_t)row * Cc + lane * 8) = make_uint4(w0, w1, w2, w3);
}

// ---------- GEMM: out[M,N] = A[M,K](bf16) @ Bt[N,K](bf16)^T + bias ----------
// grid = (N/128, M/128)  -- n fastest for A-tile L2/L3 reuse
// MODE 0: -> bf16
// MODE 1: gelu -> bf16
// MODE 2: + res(fp32) -> bf16
// MODE 3: + res(bf16) -> fp32
template<int MODE>
__global__ __launch_bounds__(256, 2)
void gemm_bt(const u16* __restrict__ A, const u16* __restrict__ Bt,
             const float* __restrict__ bias, const void* __restrict__ res,
             void* __restrict__ outp, int M, int N, int K) {
  __shared__ u16 As[128 * 32];
  __shared__ u16 Bs[128 * 32];
  const int tid  = threadIdx.x;
  const int lane = tid & 63;
  const int wave = tid >> 6;
  const int wm = (wave >> 1) * 64;
  const int wn = (wave & 1) * 64;
  const int n0 = blockIdx.x * 128;
  const int m0 = blockIdx.y * 128;
  const int quad = lane >> 4;
  const int l16  = lane & 15;

  floatx4 acc[4][4];
  #pragma unroll
  for (int i = 0; i < 4; i++)
    #pragma unroll
    for (int j = 0; j < 4; j++) acc[i][j] = (floatx4)0.f;

  // staging: chunk per thread -> LDS physical (row = tid>>2, col8 = tid&3).
  // XOR swizzle: physical col8 holds logical col8 ^ ((row>>1)&3), so the
  // source k-offset is permuted (dest of global_load_lds must stay lane-
  // contiguous; the permutation lives on the global address only).
  const int r0  = tid >> 2;
  const int cc0 = (((tid & 3) ^ ((r0 >> 1) & 3)) * 8);
  const u16* Ag = A  + (size_t)m0 * K;
  const u16* Bg = Bt + (size_t)n0 * K;

  // fragment-read swizzle: row = wm|wn + mi*16 + l16 -> ((row>>1)&3) == ((l16>>1)&3)
  const int fswz = (l16 >> 1) & 3;
  const int aoff = (quad ^ fswz) * 8;

  for (int k0 = 0; k0 < K; k0 += 32) {
    gld_lds16(Ag + (size_t)r0        * K + k0 + cc0, &As[wave * 512]);
    gld_lds16(Ag + (size_t)(r0 + 64) * K + k0 + cc0, &As[2048 + wave * 512]);
    gld_lds16(Bg + (size_t)r0        * K + k0 + cc0, &Bs[wave * 512]);
    gld_lds16(Bg + (size_t)(r0 + 64) * K + k0 + cc0, &Bs[2048 + wave * 512]);
    __syncthreads();
    short8 af[4], bf[4];
    #pragma unroll
    for (int mi = 0; mi < 4; mi++)
      af[mi] = *(const short8*)&As[(wm + mi*16 + l16) * 32 + aoff];
    #pragma unroll
    for (int ni = 0; ni < 4; ni++)
      bf[ni] = *(const short8*)&Bs[(wn + ni*16 + l16) * 32 + aoff];
    #pragma unroll
    for (int mi = 0; mi < 4; mi++)
      #pragma unroll
      for (int ni = 0; ni < 4; ni++)
        acc[mi][ni] = __builtin_amdgcn_mfma_f32_16x16x32_bf16(
            af[mi], bf[ni], acc[mi][ni], 0, 0, 0);
    __syncthreads();
  }

  const int mrow = m0 + wm + quad * 4;
  const int ncol = n0 + wn + l16;
  #pragma unroll
  for (int ni = 0; ni < 4; ni++) {
    const int n = ncol + ni * 16;
    const float bv = bias[n];
    #pragma unroll
    for (int mi = 0; mi < 4; mi++) {
      #pragma unroll
      for (int r = 0; r < 4; r++) {
        const int m = mrow + mi * 16 + r;
        const size_t idx = (size_t)m * N + n;
        float v = acc[mi][ni][r] + bv;
        if (MODE == 0)      ((u16*)outp)[idx] = f2bf(v);
        else if (MODE == 1) ((u16*)outp)[idx] = f2bf(gelu_f(v));
        else if (MODE == 2) ((u16*)outp)[idx] = f2bf(v + ((const float*)res)[idx]);
        else                ((float*)outp)[idx] = v + bf2f(((const u16*)res)[idx]);
      }
    }
  }
}

// ---------- windowed attention, one wave per (window, head) ----------
// QKV interleaved bf16 (M, 1536): [Q 512 | K 512 | V 1024..]; out (M,512) bf16.
__global__ __launch_bounds__(64)
void attn_k(const u16* __restrict__ QKV, const float* __restrict__ rel,
            u16* __restrict__ O) {
  const int win  = blockIdx.x;          // 0..1023
  const int head = blockIdx.y;          // 0..15
  const int b    = win >> 6;
  const int wh   = (win >> 3) & 7;
  const int ww   = win & 7;
  const int lane = threadIdx.x;

  __shared__ float Ks[49][36];
  __shared__ float Vs[49][36];

  const bool active = lane < 49;
  size_t rowq = 0, rowo = 0;
  float q[32];
  if (active) {
    const int i = lane / 7, j = lane - 7 * (lane / 7);
    const int l = (wh * 7 + i) * Ww + ww * 7 + j;
    const size_t gr = (size_t)(b * Ll + l);
    rowq = gr * 1536 + head * HDd;
    rowo = gr * 512  + head * HDd;
    const uint4* qp = (const uint4*)(QKV + rowq);
    const uint4* kp = (const uint4*)(QKV + rowq + 512);
    const uint4* vp = (const uint4*)(QKV + rowq + 1024);
    #pragma unroll
    for (int c = 0; c < 4; c++) {
      uint4 qv = qp[c], kv = kp[c], vv = vp[c];
      q[c*8+0] = bf2f_lo(qv.x) * SCALE; q[c*8+1] = bf2f_hi(qv.x) * SCALE;
      q[c*8+2] = bf2f_lo(qv.y) * SCALE; q[c*8+3] = bf2f_hi(qv.y) * SCALE;
      q[c*8+4] = bf2f_lo(qv.z) * SCALE; q[c*8+5] = bf2f_hi(qv.z) * SCALE;
      q[c*8+6] = bf2f_lo(qv.w) * SCALE; q[c*8+7] = bf2f_hi(qv.w) * SCALE;
      *(float4*)&Ks[lane][c*8]   = make_float4(bf2f_lo(kv.x), bf2f_hi(kv.x),
                                               bf2f_lo(kv.y), bf2f_hi(kv.y));
      *(float4*)&Ks[lane][c*8+4] = make_float4(bf2f_lo(kv.z), bf2f_hi(kv.z),
                                               bf2f_lo(kv.w), bf2f_hi(kv.w));
      *(float4*)&Vs[lane][c*8]   = make_float4(bf2f_lo(vv.x), bf2f_hi(vv.x),
                                               bf2f_lo(vv.y), bf2f_hi(vv.y));
      *(float4*)&Vs[lane][c*8+4] = make_float4(bf2f_lo(vv.z), bf2f_hi(vv.z),
                                               bf2f_lo(vv.w), bf2f_hi(vv.w));
    }
  }
  __syncthreads();
  if (!active) return;

  const float* rb = rel + ((size_t)head * 49 + lane) * 49;
  float s[49];
  float mx = -1e30f;
  #pragma unroll
  for (int m = 0; m < 49; m++) {
    float d = 0.f;
    #pragma unroll
    for (int c = 0; c < 8; c++) {
      float4 kk = *(const float4*)&Ks[m][c*4];
      d += q[c*4+0]*kk.x + q[c*4+1]*kk.y + q[c*4+2]*kk.z + q[c*4+3]*kk.w;
    }
    d += rb[m];
    s[m] = d;
    mx = fmaxf(mx, d);
  }
  float sum = 0.f;
  #pragma unroll
  for (int m = 0; m < 49; m++) { float e = __expf(s[m] - mx); s[m] = e; sum += e; }
  const float inv = 1.f / sum;

  float acc[32];
  #pragma unroll
  for (int d = 0; d < 32; d++) acc[d] = 0.f;
  #pragma unroll
  for (int m = 0; m < 49; m++) {
    const float p = s[m];
    #pragma unroll
    for (int c = 0; c < 8; c++) {
      float4 vv = *(const float4*)&Vs[m][c*4];
      acc[c*4+0] += p*vv.x; acc[c*4+1] += p*vv.y;
      acc[c*4+2] += p*vv.z; acc[c*4+3] += p*vv.w;
    }
  }
  uint4* op = (uint4*)(O + rowo);
  #pragma unroll
  for (int c = 0; c < 4; c++) {
    u32 w0 = (u32)f2bf(acc[c*8+0]*inv) | ((u32)f2bf(acc[c*8+1]*inv) << 16);
    u32 w1 = (u32)f2bf(acc[c*8+2]*inv) | ((u32)f2bf(acc[c*8+3]*inv) << 16);
    u32 w2 = (u32)f2bf(acc[c*8+4]*inv) | ((u32)f2bf(acc[c*8+5]*inv) << 16);
    u32 w3 = (u32)f2bf(acc[c*8+6]*inv) | ((u32)f2bf(acc[c*8+7]*inv) << 16);
    op[c] = make_uint4(w0, w1, w2, w3);
  }
}

// ---------- launch ----------
extern "C" void kernel_launch(void* const* d_in, const int* in_sizes, int n_in,
                              void* d_out, int out_size, void* d_ws, size_t ws_size,
                              hipStream_t stream) {
  (void)in_sizes; (void)n_in; (void)out_size; (void)ws_size;
  const float* x    = (const float*)d_in[0];
  const float* Wq   = (const float*)d_in[1];
  const float* bq   = (const float*)d_in[2];
  const float* Wk   = (const float*)d_in[3];
  const float* bk   = (const float*)d_in[4];
  const float* Wv   = (const float*)d_in[5];
  const float* bv   = (const float*)d_in[6];
  const float* Wp   = (const float*)d_in[7];
  const float* bp   = (const float*)d_in[8];
  const float* rel  = (const float*)d_in[9];
  const float* g1   = (const float*)d_in[10];
  const float* b1   = (const float*)d_in[11];
  const float* g2   = (const float*)d_in[12];
  const float* b2   = (const float*)d_in[13];
  const float* W1   = (const float*)d_in[14];
  const float* bfc1 = (const float*)d_in[15];
  const float* W2   = (const float*)d_in[16];
  const float* bfc2 = (const float*)d_in[17];
  float* out = (float*)d_out;

  // workspace layout (u16 units)
  u16* wQKV = (u16*)d_ws;                          // 1536*512
  u16* wWp  = wQKV + (size_t)1536*512;             // 512*512
  u16* wW1  = wWp  + (size_t)512*512;              // 2048*512
  u16* wW2  = wW1  + (size_t)2048*512;             // 512*2048
  float* bqkv = (float*)(wW2 + (size_t)512*2048);  // 1536 fp32
  u16* hbuf = (u16*)(bqkv + 1536);                 // M*512 (LN1 out; later LN2 out)
  u16* QKVb = hbuf + (size_t)Mm * Cc;              // M*1536 (later: MLP hidden part)
  u16* Obuf = QKVb + (size_t)Mm * 1536;            // M*512
  u16* x2bf = Obuf + (size_t)Mm * Cc;              // M*512 bf16 residual
  u16* hid  = QKVb;                                // M*2048 overlays QKVb+Obuf
  u16* h2   = hbuf;

  // weights -> bf16 transposed (QKV fused into 1536 rows)
  wcvt_k<<<(512*512)/256,  256, 0, stream>>>(Wq, wQKV,              512, 512);
  wcvt_k<<<(512*512)/256,  256, 0, stream>>>(Wk, wQKV + 512*512,    512, 512);
  wcvt_k<<<(512*512)/256,  256, 0, stream>>>(Wv, wQKV + 2*512*512,  512, 512);
  wcvt_k<<<(512*512)/256,  256, 0, stream>>>(Wp, wWp, 512, 512);
  wcvt_k<<<(512*2048)/256, 256, 0, stream>>>(W1, wW1, 512, 2048);
  wcvt_k<<<(512*2048)/256, 256, 0, stream>>>(W2, wW2, 2048, 512);
  bcat_k<<<6, 256, 0, stream>>>(bq, bk, bv, bqkv);

  // LN1
  ln_k<<<Mm/4, 256, 0, stream>>>(x, g1, b1, hbuf);

  // fused QKV projection: (M,1536)
  gemm_bt<0><<<dim3(12, Mm/128), 256, 0, stream>>>(hbuf, wQKV, bqkv, nullptr, QKVb,
                                                   Mm, 1536, 512);

  // attention
  attn_k<<<dim3(1024, 16), 64, 0, stream>>>(QKVb, rel, Obuf);

  // proj + residual(x fp32) -> x2 bf16
  gemm_bt<2><<<dim3(4, Mm/128), 256, 0, stream>>>(Obuf, wWp, bp, x, x2bf,
                                                  Mm, 512, 512);

  // LN2 (bf16 in)
  ln_bf_k<<<Mm/4, 256, 0, stream>>>(x2bf, g2, b2, h2);

  // MLP
  gemm_bt<1><<<dim3(16, Mm/128), 256, 0, stream>>>(h2, wW1, bfc1, nullptr, hid,
                                                   Mm, 2048, 512);
  gemm_bt<3><<<dim3(4, Mm/128), 256, 0, stream>>>(hid, wW2, bfc2, x2bf, out,
                                                  Mm, 512, 2048);
}

// Round 3
// 960.078 us; speedup vs baseline: 1.1902x; 1.0917x over previous
//
#include <hip/hip_runtime.h>

typedef unsigned short u16;
typedef unsigned int   u32;

using short8  = __attribute__((ext_vector_type(8))) short;
using floatx4 = __attribute__((ext_vector_type(4))) float;

// ---------- constants ----------
#define Bb   16
#define Hh   56
#define Ww   56
#define Cc   512
#define NHh  16
#define HDd  32
#define HIDh 2048
#define Ll   (Hh*Ww)          // 3136
#define Mm   (Bb*Ll)          // 50176
#define SCALE 0.17677669529663687f
#define CSTR 136              // C-tile LDS row stride (u16): 16B-aligned, bank-rotating

// ---------- helpers ----------
__device__ __forceinline__ u16 f2bf(float f) {
  union { float f; u32 u; } v; v.f = f;
  u32 r = (v.u + 0x7fffu + ((v.u >> 16) & 1u)) >> 16;
  return (u16)r;
}
__device__ __forceinline__ float bf2f(u16 u) {
  union { u32 u; float f; } v; v.u = ((u32)u) << 16; return v.f;
}
__device__ __forceinline__ float bf2f_lo(u32 u) {
  union { u32 u; float f; } v; v.u = u << 16; return v.f;
}
__device__ __forceinline__ float bf2f_hi(u32 u) {
  union { u32 u; float f; } v; v.u = u & 0xffff0000u; return v.f;
}
__device__ __forceinline__ float gelu_f(float x) {
  return 0.5f * x * (1.f + erff(x * 0.70710678118654752f));
}
__device__ __forceinline__ void gld_lds16(const u16* g, u16* l) {
  __builtin_amdgcn_global_load_lds(
      (__attribute__((address_space(1))) void*)(void*)g,
      (__attribute__((address_space(3))) void*)(void*)l,
      16, 0, 0);
}

// ---------- weight convert+transpose: Wt[n][k] = bf16(W[k][n]) ----------
__global__ void wcvt_k(const float* __restrict__ W, u16* __restrict__ Wt,
                       int K, int N) {
  int idx = blockIdx.x * 256 + threadIdx.x;     // over N*K
  int n = idx / K;
  int k = idx - n * K;
  Wt[idx] = f2bf(W[(size_t)k * N + n]);
}

// ---------- concat 3 bias vectors (512 each) ----------
__global__ void bcat_k(const float* __restrict__ a, const float* __restrict__ b,
                       const float* __restrict__ c, float* __restrict__ o) {
  int i = blockIdx.x * 256 + threadIdx.x;   // 0..1535
  float v = (i < 512) ? a[i] : (i < 1024) ? b[i - 512] : c[i - 1024];
  o[i] = v;
}

// ---------- layernorm fp32 in -> bf16 out, one wave per row ----------
__global__ __launch_bounds__(256)
void ln_k(const float* __restrict__ x, const float* __restrict__ g,
          const float* __restrict__ b, u16* __restrict__ out) {
  const int row  = blockIdx.x * 4 + (threadIdx.x >> 6);
  const int lane = threadIdx.x & 63;
  const float* xr = x + (size_t)row * Cc + lane * 8;
  float4 v0 = *(const float4*)xr;
  float4 v1 = *(const float4*)(xr + 4);
  float s  = v0.x+v0.y+v0.z+v0.w + v1.x+v1.y+v1.z+v1.w;
  float s2 = v0.x*v0.x+v0.y*v0.y+v0.z*v0.z+v0.w*v0.w
           + v1.x*v1.x+v1.y*v1.y+v1.z*v1.z+v1.w*v1.w;
  #pragma unroll
  for (int off = 32; off >= 1; off >>= 1) {
    s  += __shfl_xor(s,  off);
    s2 += __shfl_xor(s2, off);
  }
  float mu  = s  * (1.f/512.f);
  float var = s2 * (1.f/512.f) - mu*mu;
  float rs  = rsqrtf(var + 1e-5f);
  float4 ga = *(const float4*)(g + lane*8);
  float4 gb = *(const float4*)(g + lane*8 + 4);
  float4 ba = *(const float4*)(b + lane*8);
  float4 bb = *(const float4*)(b + lane*8 + 4);
  float o0 = (v0.x-mu)*rs*ga.x + ba.x;
  float o1 = (v0.y-mu)*rs*ga.y + ba.y;
  float o2 = (v0.z-mu)*rs*ga.z + ba.z;
  float o3 = (v0.w-mu)*rs*ga.w + ba.w;
  float o4 = (v1.x-mu)*rs*gb.x + bb.x;
  float o5 = (v1.y-mu)*rs*gb.y + bb.y;
  float o6 = (v1.z-mu)*rs*gb.z + bb.z;
  float o7 = (v1.w-mu)*rs*gb.w + bb.w;
  u32 w0 = (u32)f2bf(o0) | ((u32)f2bf(o1) << 16);
  u32 w1 = (u32)f2bf(o2) | ((u32)f2bf(o3) << 16);
  u32 w2 = (u32)f2bf(o4) | ((u32)f2bf(o5) << 16);
  u32 w3 = (u32)f2bf(o6) | ((u32)f2bf(o7) << 16);
  *(uint4*)(out + (size_t)row * Cc + lane * 8) = make_uint4(w0, w1, w2, w3);
}

// ---------- layernorm bf16 in -> bf16 out ----------
__global__ __launch_bounds__(256)
void ln_bf_k(const u16* __restrict__ x, const float* __restrict__ g,
             const float* __restrict__ b, u16* __restrict__ out) {
  const int row  = blockIdx.x * 4 + (threadIdx.x >> 6);
  const int lane = threadIdx.x & 63;
  uint4 xv = *(const uint4*)(x + (size_t)row * Cc + lane * 8);
  float v[8];
  v[0]=bf2f_lo(xv.x); v[1]=bf2f_hi(xv.x); v[2]=bf2f_lo(xv.y); v[3]=bf2f_hi(xv.y);
  v[4]=bf2f_lo(xv.z); v[5]=bf2f_hi(xv.z); v[6]=bf2f_lo(xv.w); v[7]=bf2f_hi(xv.w);
  float s = 0.f, s2 = 0.f;
  #pragma unroll
  for (int i = 0; i < 8; i++) { s += v[i]; s2 += v[i]*v[i]; }
  #pragma unroll
  for (int off = 32; off >= 1; off >>= 1) {
    s  += __shfl_xor(s,  off);
    s2 += __shfl_xor(s2, off);
  }
  float mu  = s  * (1.f/512.f);
  float var = s2 * (1.f/512.f) - mu*mu;
  float rs  = rsqrtf(var + 1e-5f);
  float4 ga = *(const float4*)(g + lane*8);
  float4 gb = *(const float4*)(g + lane*8 + 4);
  float4 ba = *(const float4*)(b + lane*8);
  float4 bb = *(const float4*)(b + lane*8 + 4);
  float o[8];
  o[0]=(v[0]-mu)*rs*ga.x+ba.x; o[1]=(v[1]-mu)*rs*ga.y+ba.y;
  o[2]=(v[2]-mu)*rs*ga.z+ba.z; o[3]=(v[3]-mu)*rs*ga.w+ba.w;
  o[4]=(v[4]-mu)*rs*gb.x+bb.x; o[5]=(v[5]-mu)*rs*gb.y+bb.y;
  o[6]=(v[6]-mu)*rs*gb.z+bb.z; o[7]=(v[7]-mu)*rs*gb.w+bb.w;
  u32 w0 = (u32)f2bf(o[0]) | ((u32)f2bf(o[1]) << 16);
  u32 w1 = (u32)f2bf(o[2]) | ((u32)f2bf(o[3]) << 16);
  u32 w2 = (u32)f2bf(o[4]) | ((u32)f2bf(o[5]) << 16);
  u32 w3 = (u32)f2bf(o[6]) | ((u32)f2bf(o[7]) << 16);
  *(uint4*)(out + (size_t)row * Cc + lane * 8) = make_uint4(w0, w1, w2, w3);
}

// ---------- GEMM: out[M,N] = A[M,K](bf16) @ Bt[N,K](bf16)^T + bias ----------
// 1-D grid, XCD-aware swizzle: xcd = b&7 owns m-tiles mt ≡ xcd (mod 8),
// n fastest within an XCD -> each A-tile lives in exactly one XCD L2.
// MODE 0: -> bf16   MODE 1: gelu -> bf16   MODE 2: +res(fp32) -> bf16
// MODE 3: +res(bf16) -> fp32 (direct stores: fp32 rows are full-line already)
template<int MODE>
__global__ __launch_bounds__(256, 2)
void gemm_bt(const u16* __restrict__ A, const u16* __restrict__ Bt,
             const float* __restrict__ bias, const void* __restrict__ res,
             void* __restrict__ outp, int M, int N, int K, int nbn) {
  __shared__ __align__(16) u16 smem[128 * CSTR];   // 34816 B; aliases staging+C
  u16* As = smem;                                  // 128*32
  u16* Bs = smem + 4096;                           // 128*32

  const int b   = blockIdx.x;
  const int xcd = b & 7;
  const int s   = b >> 3;
  const int mt  = (s / nbn) * 8 + xcd;
  const int nt  = s - (s / nbn) * nbn;
  const int m0  = mt * 128;
  const int n0  = nt * 128;

  const int tid  = threadIdx.x;
  const int lane = tid & 63;
  const int wave = tid >> 6;
  const int wm = (wave >> 1) * 64;
  const int wn = (wave & 1) * 64;
  const int quad = lane >> 4;
  const int l16  = lane & 15;

  floatx4 acc[4][4];
  #pragma unroll
  for (int i = 0; i < 4; i++)
    #pragma unroll
    for (int j = 0; j < 4; j++) acc[i][j] = (floatx4)0.f;

  const int r0  = tid >> 2;
  const int cc0 = (((tid & 3) ^ ((r0 >> 1) & 3)) * 8);   // XOR-swizzled k-offset
  const u16* Ag = A  + (size_t)m0 * K;
  const u16* Bg = Bt + (size_t)n0 * K;

  const int fswz = (l16 >> 1) & 3;
  const int aoff = (quad ^ fswz) * 8;

  for (int k0 = 0; k0 < K; k0 += 32) {
    gld_lds16(Ag + (size_t)r0        * K + k0 + cc0, &As[wave * 512]);
    gld_lds16(Ag + (size_t)(r0 + 64) * K + k0 + cc0, &As[2048 + wave * 512]);
    gld_lds16(Bg + (size_t)r0        * K + k0 + cc0, &Bs[wave * 512]);
    gld_lds16(Bg + (size_t)(r0 + 64) * K + k0 + cc0, &Bs[2048 + wave * 512]);
    __syncthreads();
    short8 af[4], bf[4];
    #pragma unroll
    for (int mi = 0; mi < 4; mi++)
      af[mi] = *(const short8*)&As[(wm + mi*16 + l16) * 32 + aoff];
    #pragma unroll
    for (int ni = 0; ni < 4; ni++)
      bf[ni] = *(const short8*)&Bs[(wn + ni*16 + l16) * 32 + aoff];
    #pragma unroll
    for (int mi = 0; mi < 4; mi++)
      #pragma unroll
      for (int ni = 0; ni < 4; ni++)
        acc[mi][ni] = __builtin_amdgcn_mfma_f32_16x16x32_bf16(
            af[mi], bf[ni], acc[mi][ni], 0, 0, 0);
    __syncthreads();
  }

  if (MODE == 3) {
    // fp32 direct stores: 16 lanes x 4B consecutive = full 64B lines.
    const int mrow = m0 + wm + quad * 4;
    const int ncol = n0 + wn + l16;
    #pragma unroll
    for (int ni = 0; ni < 4; ni++) {
      const int n = ncol + ni * 16;
      const float bv = bias[n];
      #pragma unroll
      for (int mi = 0; mi < 4; mi++)
        #pragma unroll
        for (int r = 0; r < 4; r++) {
          const size_t idx = (size_t)(mrow + mi * 16 + r) * N + n;
          ((float*)outp)[idx] = acc[mi][ni][r] + bv + bf2f(((const u16*)res)[idx]);
        }
    }
  } else {
    // stage bf16 C-tile in LDS, then coalesced 16B/lane writeout
    #pragma unroll
    for (int ni = 0; ni < 4; ni++) {
      const int col = wn + ni * 16 + l16;
      const float bv = bias[n0 + col];
      #pragma unroll
      for (int mi = 0; mi < 4; mi++)
        #pragma unroll
        for (int r = 0; r < 4; r++) {
          float v = acc[mi][ni][r] + bv;
          if (MODE == 1) v = gelu_f(v);
          smem[(wm + mi * 16 + quad * 4 + r) * CSTR + col] = f2bf(v);
        }
    }
    __syncthreads();
    const int trow = tid >> 4;            // 0..15
    const int tcol = (tid & 15) * 8;      // u16 col
    #pragma unroll
    for (int it = 0; it < 8; it++) {
      const int row = it * 16 + trow;
      uint4 w = *(const uint4*)&smem[row * CSTR + tcol];
      const size_t gi = (size_t)(m0 + row) * N + n0 + tcol;
      if (MODE == 2) {
        const float* rp = (const float*)res + gi;
        float4 ra = *(const float4*)rp;
        float4 rb = *(const float4*)(rp + 4);
        u32 w0 = (u32)f2bf(bf2f_lo(w.x) + ra.x) | ((u32)f2bf(bf2f_hi(w.x) + ra.y) << 16);
        u32 w1 = (u32)f2bf(bf2f_lo(w.y) + ra.z) | ((u32)f2bf(bf2f_hi(w.y) + ra.w) << 16);
        u32 w2 = (u32)f2bf(bf2f_lo(w.z) + rb.x) | ((u32)f2bf(bf2f_hi(w.z) + rb.y) << 16);
        u32 w3 = (u32)f2bf(bf2f_lo(w.w) + rb.z) | ((u32)f2bf(bf2f_hi(w.w) + rb.w) << 16);
        *(uint4*)((u16*)outp + gi) = make_uint4(w0, w1, w2, w3);
      } else {
        *(uint4*)((u16*)outp + gi) = w;
      }
    }
  }
}

// ---------- windowed attention, one wave per (window, head) ----------
// QKV interleaved bf16 (M, 1536): [Q 512 | K 512 | V 512]; out (M,512) bf16.
__global__ __launch_bounds__(64)
void attn_k(const u16* __restrict__ QKV, const float* __restrict__ rel,
            u16* __restrict__ O) {
  const int win  = blockIdx.x;          // 0..1023
  const int head = blockIdx.y;          // 0..15
  const int b    = win >> 6;
  const int wh   = (win >> 3) & 7;
  const int ww   = win & 7;
  const int lane = threadIdx.x;

  __shared__ float Ks[49][36];
  __shared__ float Vs[49][36];

  const bool active = lane < 49;
  size_t rowq = 0, rowo = 0;
  float q[32];
  if (active) {
    const int i = lane / 7, j = lane - 7 * (lane / 7);
    const int l = (wh * 7 + i) * Ww + ww * 7 + j;
    const size_t gr = (size_t)(b * Ll + l);
    rowq = gr * 1536 + head * HDd;
    rowo = gr * 512  + head * HDd;
    const uint4* qp = (const uint4*)(QKV + rowq);
    const uint4* kp = (const uint4*)(QKV + rowq + 512);
    const uint4* vp = (const uint4*)(QKV + rowq + 1024);
    #pragma unroll
    for (int c = 0; c < 4; c++) {
      uint4 qv = qp[c], kv = kp[c], vv = vp[c];
      q[c*8+0] = bf2f_lo(qv.x) * SCALE; q[c*8+1] = bf2f_hi(qv.x) * SCALE;
      q[c*8+2] = bf2f_lo(qv.y) * SCALE; q[c*8+3] = bf2f_hi(qv.y) * SCALE;
      q[c*8+4] = bf2f_lo(qv.z) * SCALE; q[c*8+5] = bf2f_hi(qv.z) * SCALE;
      q[c*8+6] = bf2f_lo(qv.w) * SCALE; q[c*8+7] = bf2f_hi(qv.w) * SCALE;
      *(float4*)&Ks[lane][c*8]   = make_float4(bf2f_lo(kv.x), bf2f_hi(kv.x),
                                               bf2f_lo(kv.y), bf2f_hi(kv.y));
      *(float4*)&Ks[lane][c*8+4] = make_float4(bf2f_lo(kv.z), bf2f_hi(kv.z),
                                               bf2f_lo(kv.w), bf2f_hi(kv.w));
      *(float4*)&Vs[lane][c*8]   = make_float4(bf2f_lo(vv.x), bf2f_hi(vv.x),
                                               bf2f_lo(vv.y), bf2f_hi(vv.y));
      *(float4*)&Vs[lane][c*8+4] = make_float4(bf2f_lo(vv.z), bf2f_hi(vv.z),
                                               bf2f_lo(vv.w), bf2f_hi(vv.w));
    }
  }
  __syncthreads();
  if (!active) return;

  const float* rb = rel + ((size_t)head * 49 + lane) * 49;
  float s[49];
  float mx = -1e30f;
  #pragma unroll
  for (int m = 0; m < 49; m++) {
    float d = 0.f;
    #pragma unroll
    for (int c = 0; c < 8; c++) {
      float4 kk = *(const float4*)&Ks[m][c*4];
      d += q[c*4+0]*kk.x + q[c*4+1]*kk.y + q[c*4+2]*kk.z + q[c*4+3]*kk.w;
    }
    d += rb[m];
    s[m] = d;
    mx = fmaxf(mx, d);
  }
  float sum = 0.f;
  #pragma unroll
  for (int m = 0; m < 49; m++) { float e = __expf(s[m] - mx); s[m] = e; sum += e; }
  const float inv = 1.f / sum;

  float acc[32];
  #pragma unroll
  for (int d = 0; d < 32; d++) acc[d] = 0.f;
  #pragma unroll
  for (int m = 0; m < 49; m++) {
    const float p = s[m];
    #pragma unroll
    for (int c = 0; c < 8; c++) {
      float4 vv = *(const float4*)&Vs[m][c*4];
      acc[c*4+0] += p*vv.x; acc[c*4+1] += p*vv.y;
      acc[c*4+2] += p*vv.z; acc[c*4+3] += p*vv.w;
    }
  }
  uint4* op = (uint4*)(O + rowo);
  #pragma unroll
  for (int c = 0; c < 4; c++) {
    u32 w0 = (u32)f2bf(acc[c*8+0]*inv) | ((u32)f2bf(acc[c*8+1]*inv) << 16);
    u32 w1 = (u32)f2bf(acc[c*8+2]*inv) | ((u32)f2bf(acc[c*8+3]*inv) << 16);
    u32 w2 = (u32)f2bf(acc[c*8+4]*inv) | ((u32)f2bf(acc[c*8+5]*inv) << 16);
    u32 w3 = (u32)f2bf(acc[c*8+6]*inv) | ((u32)f2bf(acc[c*8+7]*inv) << 16);
    op[c] = make_uint4(w0, w1, w2, w3);
  }
}

// ---------- launch ----------
extern "C" void kernel_launch(void* const* d_in, const int* in_sizes, int n_in,
                              void* d_out, int out_size, void* d_ws, size_t ws_size,
                              hipStream_t stream) {
  (void)in_sizes; (void)n_in; (void)out_size; (void)ws_size;
  const float* x    = (const float*)d_in[0];
  const float* Wq   = (const float*)d_in[1];
  const float* bq   = (const float*)d_in[2];
  const float* Wk   = (const float*)d_in[3];
  const float* bk   = (const float*)d_in[4];
  const float* Wv   = (const float*)d_in[5];
  const float* bv   = (const float*)d_in[6];
  const float* Wp   = (const float*)d_in[7];
  const float* bp   = (const float*)d_in[8];
  const float* rel  = (const float*)d_in[9];
  const float* g1   = (const float*)d_in[10];
  const float* b1   = (const float*)d_in[11];
  const float* g2   = (const float*)d_in[12];
  const float* b2   = (const float*)d_in[13];
  const float* W1   = (const float*)d_in[14];
  const float* bfc1 = (const float*)d_in[15];
  const float* W2   = (const float*)d_in[16];
  const float* bfc2 = (const float*)d_in[17];
  float* out = (float*)d_out;

  // workspace layout (u16 units)
  u16* wQKV = (u16*)d_ws;                          // 1536*512
  u16* wWp  = wQKV + (size_t)1536*512;             // 512*512
  u16* wW1  = wWp  + (size_t)512*512;              // 2048*512
  u16* wW2  = wW1  + (size_t)2048*512;             // 512*2048
  float* bqkv = (float*)(wW2 + (size_t)512*2048);  // 1536 fp32
  u16* hbuf = (u16*)(bqkv + 1536);                 // M*512 (LN1 out; later LN2 out)
  u16* QKVb = hbuf + (size_t)Mm * Cc;              // M*1536 (later: MLP hidden part)
  u16* Obuf = QKVb + (size_t)Mm * 1536;            // M*512
  u16* x2bf = Obuf + (size_t)Mm * Cc;              // M*512 bf16 residual
  u16* hid  = QKVb;                                // M*2048 overlays QKVb+Obuf
  u16* h2   = hbuf;

  // weights -> bf16 transposed (QKV fused into 1536 rows)
  wcvt_k<<<(512*512)/256,  256, 0, stream>>>(Wq, wQKV,              512, 512);
  wcvt_k<<<(512*512)/256,  256, 0, stream>>>(Wk, wQKV + 512*512,    512, 512);
  wcvt_k<<<(512*512)/256,  256, 0, stream>>>(Wv, wQKV + 2*512*512,  512, 512);
  wcvt_k<<<(512*512)/256,  256, 0, stream>>>(Wp, wWp, 512, 512);
  wcvt_k<<<(512*2048)/256, 256, 0, stream>>>(W1, wW1, 512, 2048);
  wcvt_k<<<(512*2048)/256, 256, 0, stream>>>(W2, wW2, 2048, 512);
  bcat_k<<<6, 256, 0, stream>>>(bq, bk, bv, bqkv);

  // LN1
  ln_k<<<Mm/4, 256, 0, stream>>>(x, g1, b1, hbuf);

  // fused QKV projection: (M,1536), 392*12 blocks
  gemm_bt<0><<<392*12, 256, 0, stream>>>(hbuf, wQKV, bqkv, nullptr, QKVb,
                                         Mm, 1536, 512, 12);

  // attention
  attn_k<<<dim3(1024, 16), 64, 0, stream>>>(QKVb, rel, Obuf);

  // proj + residual(x fp32) -> x2 bf16
  gemm_bt<2><<<392*4, 256, 0, stream>>>(Obuf, wWp, bp, x, x2bf,
                                        Mm, 512, 512, 4);

  // LN2 (bf16 in)
  ln_bf_k<<<Mm/4, 256, 0, stream>>>(x2bf, g2, b2, h2);

  // MLP
  gemm_bt<1><<<392*16, 256, 0, stream>>>(h2, wW1, bfc1, nullptr, hid,
                                         Mm, 2048, 512, 16);
  gemm_bt<3><<<392*4, 256, 0, stream>>>(hid, wW2, bfc2, x2bf, out,
                                        Mm, 512, 2048, 4);
}